// Round 5
// baseline (175.355 us; speedup 1.0000x reference)
//
#include <hip/hip_runtime.h>
#include <math.h>

// Split-KV flash attention, B=64, L=1024, D=64, fp32 in/out.
// out = softmax(mask(Q K^T / 8)) V ; key >= valid_len[b] -> -1e6 -> exp == 0 exactly.
// Each (b, qtile) is split over S KV-chunks; chunk blocks write unnormalized
// partials (acc, m, l in exp2 domain) to ws; reduce_k combines. Chunks fully
// beyond valid are skipped exactly. S picked from ws_size (4 -> 2 -> 1).

typedef __attribute__((ext_vector_type(4))) float f32x4;
typedef __attribute__((ext_vector_type(8))) short bf16x8;
typedef __attribute__((ext_vector_type(8))) unsigned short u16x8;

constexpr int Bn = 64, Ln = 1024, Dn = 64;
constexpr int NROW = Bn * Ln;                               // 65536 query rows
constexpr float QSCALE = 0.125f * 1.44269504088896340736f;  // 1/sqrt(64) * log2(e)
constexpr float DEFER_THR = 10.0f;   // log2 domain: deferred p bounded by 2^10

__device__ inline unsigned short f2bf(float x) {  // round-to-nearest-even
    unsigned int u = __float_as_uint(x);
    return (unsigned short)((u + 0x7fffu + ((u >> 16) & 1u)) >> 16);
}

__global__ __launch_bounds__(256) void flash_attn(
    const float* __restrict__ Q, const float* __restrict__ K,
    const float* __restrict__ V, const int* __restrict__ VL,
    float* __restrict__ O, float* __restrict__ ws, int S)
{
    __shared__ unsigned short kls[64 * 64];      // K tile [kv][d] bf16, XOR-swizzled
    __shared__ unsigned short vls[64 * 64];      // V tile [d][kv] bf16, XOR-swizzled
    __shared__ unsigned short plds[4][16 * 64];  // per-wave P [q][kv], XOR-swizzled

    const int tid = threadIdx.x;
    const int w = tid >> 6, l = tid & 63;
    const int lg = l >> 4, ln = l & 15;
    const int blk = blockIdx.x;
    const int c = blk % S;          // KV chunk
    const int bq = blk / S;
    const int b = bq >> 4;
    const int qt = bq & 15;
    const int qbase = qt * 64 + w * 16;
    const int valid = VL[b];

    const int nkt_total = (valid + 63) >> 6;   // tiles beyond valid contribute exactly 0
    const int tpc = 16 / S;                    // tiles per chunk
    const int t0 = c * tpc;
    const int t1 = min(nkt_total, t0 + tpc);
    if (t0 >= t1) return;                      // block-uniform: whole chunk masked

    const float* Kbase = K + (size_t)b * Ln * Dn;
    const float* Vbase = V + (size_t)b * Ln * Dn;

    // ---- Q A-fragments: f32 load, fold QSCALE, convert to bf16 ----
    bf16x8 aq0, aq1;
    {
        const f32x4* qp = reinterpret_cast<const f32x4*>(Q + ((size_t)b * Ln + qbase + ln) * Dn);
        f32x4 q0 = qp[lg * 2], q1 = qp[lg * 2 + 1], q2 = qp[8 + lg * 2], q3 = qp[8 + lg * 2 + 1];
        #pragma unroll
        for (int j = 0; j < 4; ++j) {
            aq0[j]     = (short)f2bf(q0[j] * QSCALE);
            aq0[j + 4] = (short)f2bf(q1[j] * QSCALE);
            aq1[j]     = (short)f2bf(q2[j] * QSCALE);
            aq1[j + 4] = (short)f2bf(q3[j] * QSCALE);
        }
    }

    // staging thread mapping
    const int kr = tid >> 2, kc = (tid & 3) * 16;  // K: row kr, cols kc..kc+15
    const int vd = l, vk0 = w * 16;                // V: d = lane, k = vk0..vk0+15

    // prefetch registers (T14: issue early, write late)
    f32x4 kpre[4];
    float vpre[16];
    {   // prologue: first tile of this chunk
        const f32x4* kp = reinterpret_cast<const f32x4*>(Kbase + (size_t)(t0 * 64 + kr) * Dn + kc);
        #pragma unroll
        for (int i = 0; i < 4; ++i) kpre[i] = kp[i];
        const float* vp = Vbase + (size_t)(t0 * 64 + vk0) * Dn + vd;
        #pragma unroll
        for (int i = 0; i < 16; ++i) vpre[i] = vp[(size_t)i * Dn];
    }

    f32x4 acc[4] = {{0.f,0.f,0.f,0.f},{0.f,0.f,0.f,0.f},{0.f,0.f,0.f,0.f},{0.f,0.f,0.f,0.f}};
    float mrow[4] = {-1e30f, -1e30f, -1e30f, -1e30f};
    float lrow[4] = {0.f, 0.f, 0.f, 0.f};
    unsigned short* pw = plds[w];
    char* klsb = reinterpret_cast<char*>(kls);
    char* vlsb = reinterpret_cast<char*>(vls);
    char* pwb  = reinterpret_cast<char*>(pw);

    for (int kt = t0; kt < t1; ++kt) {
        __syncthreads();   // prior tile's LDS reads complete
        // ---- staged regs -> LDS (convert f32->bf16) ----
        {
            u16x8 c0, c1;
            #pragma unroll
            for (int j = 0; j < 4; ++j) {
                c0[j]     = f2bf(kpre[0][j]);  c0[j + 4] = f2bf(kpre[1][j]);
                c1[j]     = f2bf(kpre[2][j]);  c1[j + 4] = f2bf(kpre[3][j]);
            }
            const int kb = kr * 128 + kc * 2, ksw = (kr & 7) << 4;
            *reinterpret_cast<u16x8*>(klsb + ((kb)      ^ ksw)) = c0;
            *reinterpret_cast<u16x8*>(klsb + ((kb + 16) ^ ksw)) = c1;
            u16x8 v0, v1;
            #pragma unroll
            for (int j = 0; j < 8; ++j) { v0[j] = f2bf(vpre[j]); v1[j] = f2bf(vpre[j + 8]); }
            const int vb = vd * 128 + vk0 * 2, vsw = (vd & 7) << 4;
            *reinterpret_cast<u16x8*>(vlsb + ((vb)      ^ vsw)) = v0;
            *reinterpret_cast<u16x8*>(vlsb + ((vb + 16) ^ vsw)) = v1;
        }
        __syncthreads();

        // ---- issue next tile's global loads (consumed next iteration) ----
        if (kt + 1 < t1) {
            const f32x4* kp = reinterpret_cast<const f32x4*>(Kbase + (size_t)((kt + 1) * 64 + kr) * Dn + kc);
            #pragma unroll
            for (int i = 0; i < 4; ++i) kpre[i] = kp[i];
            const float* vp = Vbase + (size_t)((kt + 1) * 64 + vk0) * Dn + vd;
            #pragma unroll
            for (int i = 0; i < 16; ++i) vpre[i] = vp[(size_t)i * Dn];
        }

        // ---- QK^T: S[16q x 64k] (already in exp2-scaled domain) ----
        f32x4 st[4] = {{0.f,0.f,0.f,0.f},{0.f,0.f,0.f,0.f},{0.f,0.f,0.f,0.f},{0.f,0.f,0.f,0.f}};
        #pragma unroll
        for (int t = 0; t < 4; ++t) {
            const int r = 16 * t + ln, rsw = (r & 7) << 4;
            bf16x8 bk0 = *reinterpret_cast<const bf16x8*>(klsb + ((r * 128 + lg * 16)      ^ rsw));
            st[t] = __builtin_amdgcn_mfma_f32_16x16x32_bf16(aq0, bk0, st[t], 0, 0, 0);
            bf16x8 bk1 = *reinterpret_cast<const bf16x8*>(klsb + ((r * 128 + lg * 16 + 64) ^ rsw));
            st[t] = __builtin_amdgcn_mfma_f32_16x16x32_bf16(aq1, bk1, st[t], 0, 0, 0);
        }

        // ---- mask (only the partial last tile; wave-uniform branch) ----
        const int kbase = kt * 64;
        if (kbase + 64 > valid) {
            #pragma unroll
            for (int t = 0; t < 4; ++t) {
                const bool msk = (kbase + 16 * t + ln) >= valid;
                #pragma unroll
                for (int j = 0; j < 4; ++j) if (msk) st[t][j] = -1e30f;
            }
        }

        // ---- online softmax with deferred rescale (T13) ----
        float mx[4];
        #pragma unroll
        for (int j = 0; j < 4; ++j) {
            float m0 = fmaxf(fmaxf(st[0][j], st[1][j]), fmaxf(st[2][j], st[3][j]));
            #pragma unroll
            for (int off = 8; off >= 1; off >>= 1) m0 = fmaxf(m0, __shfl_xor(m0, off, 64));
            mx[j] = m0;
        }
        const float g = fmaxf(fmaxf(mx[0] - mrow[0], mx[1] - mrow[1]),
                              fmaxf(mx[2] - mrow[2], mx[3] - mrow[3]));
        if (__any(g > DEFER_THR)) {
            #pragma unroll
            for (int j = 0; j < 4; ++j) {
                const float mn = fmaxf(mrow[j], mx[j]);
                const float rs = exp2f(mrow[j] - mn);
                mrow[j] = mn;
                lrow[j] *= rs;
                #pragma unroll
                for (int t = 0; t < 4; ++t) acc[t][j] *= rs;
            }
        }
        #pragma unroll
        for (int j = 0; j < 4; ++j) {
            const int q = lg * 4 + j, qsw = (q & 7) << 4;
            float rs = 0.f;
            #pragma unroll
            for (int t = 0; t < 4; ++t) {
                const float p = exp2f(st[t][j] - mrow[j]);   // masked -> exp2(-huge) == 0
                rs += p;
                const int col = 16 * t + ln;
                *reinterpret_cast<unsigned short*>(pwb + ((q * 128 + col * 2) ^ qsw)) = f2bf(p);
            }
            #pragma unroll
            for (int off = 8; off >= 1; off >>= 1) rs += __shfl_xor(rs, off, 64);
            lrow[j] += rs;
        }
        // no __syncthreads: plds is per-wave; intra-wave DS ops are in-order and
        // the compiler inserts lgkmcnt before the aliasing reads below.

        // ---- PV: acc[16q x 64d] += P[16q x 64k] * V[64k x 64d] ----
        #pragma unroll
        for (int s = 0; s < 2; ++s) {
            bf16x8 pa = *reinterpret_cast<const bf16x8*>(
                pwb + ((ln * 128 + lg * 16 + 64 * s) ^ ((ln & 7) << 4)));
            #pragma unroll
            for (int t = 0; t < 4; ++t) {
                const int r = 16 * t + ln, rsw = (r & 7) << 4;
                bf16x8 bv = *reinterpret_cast<const bf16x8*>(vlsb + ((r * 128 + lg * 16 + 64 * s) ^ rsw));
                acc[t] = __builtin_amdgcn_mfma_f32_16x16x32_bf16(pa, bv, acc[t], 0, 0, 0);
            }
        }
    }

    // ---- epilogue ----
    if (S == 1) {
        float inv[4];
        #pragma unroll
        for (int j = 0; j < 4; ++j) inv[j] = 1.0f / lrow[j];
        float* Orow = O + ((size_t)b * Ln + qbase) * Dn;
        #pragma unroll
        for (int t = 0; t < 4; ++t) {
            #pragma unroll
            for (int j = 0; j < 4; ++j) {
                const int q = lg * 4 + j;
                const int d = 16 * t + ln;
                Orow[(size_t)q * Dn + d] = acc[t][j] * inv[j];
            }
        }
    } else {
        // unnormalized partials: acc (relative to mrow), mrow, lrow
        float* accb = ws;
        float* mb = ws + (size_t)S * NROW * Dn;
        float* lb = mb + (size_t)S * NROW;
        const int rowbase = b * Ln + qbase;
        #pragma unroll
        for (int t = 0; t < 4; ++t) {
            #pragma unroll
            for (int j = 0; j < 4; ++j) {
                const int row = rowbase + lg * 4 + j;
                const int d = 16 * t + ln;
                accb[((size_t)c * NROW + row) * Dn + d] = acc[t][j];
            }
        }
        if (ln == 0) {
            #pragma unroll
            for (int j = 0; j < 4; ++j) {
                const int row = rowbase + lg * 4 + j;
                mb[(size_t)c * NROW + row] = mrow[j];
                lb[(size_t)c * NROW + row] = lrow[j];
            }
        }
    }
}

__global__ __launch_bounds__(256) void reduce_k(
    const float* __restrict__ ws, const int* __restrict__ VL,
    float* __restrict__ O, int S)
{
    const int gid = blockIdx.x * 256 + threadIdx.x;   // over NROW*Dn
    const int r = gid >> 6, d = gid & 63;
    const int b = r >> 10;
    const int valid = VL[b];
    const int CH = Ln / S;
    const int nc = min(S, (valid + CH - 1) / CH);

    const float* accb = ws;
    const float* mb = ws + (size_t)S * NROW * Dn;
    const float* lb = mb + (size_t)S * NROW;

    float m = -1e30f;
    for (int c = 0; c < nc; ++c) m = fmaxf(m, mb[(size_t)c * NROW + r]);
    float o = 0.f, L = 0.f;
    for (int c = 0; c < nc; ++c) {
        const float e = exp2f(mb[(size_t)c * NROW + r] - m);
        o += accb[((size_t)c * NROW + r) * Dn + d] * e;
        L += lb[(size_t)c * NROW + r] * e;
    }
    O[(size_t)r * Dn + d] = o / L;
}

extern "C" void kernel_launch(void* const* d_in, const int* in_sizes, int n_in,
                              void* d_out, int out_size, void* d_ws, size_t ws_size,
                              hipStream_t stream) {
    const float* Q = (const float*)d_in[0];
    const float* K = (const float*)d_in[1];
    const float* V = (const float*)d_in[2];
    const int* VL = (const int*)d_in[3];
    float* O = (float*)d_out;
    float* ws = (float*)d_ws;

    const size_t per_chunk = ((size_t)NROW * Dn + 2 * (size_t)NROW) * sizeof(float); // ~17.3 MB
    int S = 1;
    if (ws_size >= 4 * per_chunk) S = 4;
    else if (ws_size >= 2 * per_chunk) S = 2;

    flash_attn<<<Bn * 16 * S, 256, 0, stream>>>(Q, K, V, VL, O, ws, S);
    if (S > 1)
        reduce_k<<<NROW * Dn / 256, 256, 0, stream>>>(ws, VL, O, S);
}

// Round 7
// 127.180 us; speedup vs baseline: 1.3788x; 1.3788x over previous
//
#include <hip/hip_runtime.h>
#include <math.h>

// Fused flash attention, B=64, L=1024, D=64, fp32 in/out.
// out = softmax(mask(Q K^T / 8)) V ; key >= valid_len[b] -> -1e6 -> exp == 0 exactly,
// so KV tiles >= valid are skipped (exact). exp2 domain, QSCALE folded into Q.
// Swapped-operand QK^T: st = mfma(A=K, B=Q) so lane ln owns q-row ln ->
// softmax row-reduce = in-register tree + 2 shuffles; P-store = 4 x ds_write_b64.
// K/V LDS double-buffered: 1 barrier per tile.

typedef __attribute__((ext_vector_type(4))) float f32x4;
typedef __attribute__((ext_vector_type(8))) short bf16x8;
typedef __attribute__((ext_vector_type(8))) unsigned short u16x8;
typedef __attribute__((ext_vector_type(4))) unsigned short u16x4;

constexpr int Bn = 64, Ln = 1024, Dn = 64;
constexpr float QSCALE = 0.125f * 1.44269504088896340736f;  // 1/sqrt(64) * log2(e)
constexpr float DEFER_THR = 10.0f;   // log2 domain: deferred p bounded by 2^10

__device__ inline unsigned short f2bf(float x) {  // round-to-nearest-even
    unsigned int u = __float_as_uint(x);
    return (unsigned short)((u + 0x7fffu + ((u >> 16) & 1u)) >> 16);
}

__global__ __launch_bounds__(256) void flash_attn(
    const float* __restrict__ Q, const float* __restrict__ K,
    const float* __restrict__ V, const int* __restrict__ VL,
    float* __restrict__ O)
{
    __shared__ unsigned short kls[2][64 * 64];   // K tile [kv][d] bf16, XOR-swizzled
    __shared__ unsigned short vls[2][64 * 64];   // V tile [d][kv] bf16, XOR-swizzled
    __shared__ unsigned short plds[4][16 * 64];  // per-wave P [q][k], XOR-swizzled

    const int tid = threadIdx.x;
    const int w = tid >> 6, l = tid & 63;
    const int lg = l >> 4, ln = l & 15;
    const int b = blockIdx.x >> 4;
    const int qt = blockIdx.x & 15;
    const int qbase = qt * 64 + w * 16;
    const int valid = VL[b];
    const int nkt = (valid + 63) >> 6;   // tiles beyond valid contribute exactly 0

    const float* Kbase = K + (size_t)b * Ln * Dn;
    const float* Vbase = V + (size_t)b * Ln * Dn;

    // ---- Q B-fragments (swapped-QK): same per-lane bytes as the A-frag form ----
    bf16x8 bq0, bq1;
    {
        const f32x4* qp = reinterpret_cast<const f32x4*>(Q + ((size_t)b * Ln + qbase + ln) * Dn);
        f32x4 q0 = qp[lg * 2], q1 = qp[lg * 2 + 1], q2 = qp[8 + lg * 2], q3 = qp[8 + lg * 2 + 1];
        #pragma unroll
        for (int j = 0; j < 4; ++j) {
            bq0[j]     = (short)f2bf(q0[j] * QSCALE);
            bq0[j + 4] = (short)f2bf(q1[j] * QSCALE);
            bq1[j]     = (short)f2bf(q2[j] * QSCALE);
            bq1[j + 4] = (short)f2bf(q3[j] * QSCALE);
        }
    }

    // staging thread mapping
    const int kr = tid >> 2, kc = (tid & 3) * 16;  // K: row kr, cols kc..kc+15
    const int vd = l, vk0 = w * 16;                // V: d = lane, k = vk0..vk0+15

    f32x4 kpre[4];
    float vpre[16];

    char* const kls0 = reinterpret_cast<char*>(kls[0]);
    char* const kls1 = reinterpret_cast<char*>(kls[1]);
    char* const vls0 = reinterpret_cast<char*>(vls[0]);
    char* const vls1 = reinterpret_cast<char*>(vls[1]);
    char* const pwb  = reinterpret_cast<char*>(plds[w]);

    const int kb = kr * 128 + kc * 2, ksw = (kr & 7) << 4;
    const int vb = vd * 128 + vk0 * 2, vsw = (vd & 7) << 4;

    // stage helper: convert kpre/vpre -> bf16, write into buffer p
    auto stage_write = [&](int p) {
        char* kd = p ? kls1 : kls0;
        char* vd_ = p ? vls1 : vls0;
        u16x8 c0, c1;
        #pragma unroll
        for (int j = 0; j < 4; ++j) {
            c0[j]     = f2bf(kpre[0][j]);  c0[j + 4] = f2bf(kpre[1][j]);
            c1[j]     = f2bf(kpre[2][j]);  c1[j + 4] = f2bf(kpre[3][j]);
        }
        *reinterpret_cast<u16x8*>(kd + ((kb)      ^ ksw)) = c0;
        *reinterpret_cast<u16x8*>(kd + ((kb + 16) ^ ksw)) = c1;
        u16x8 v0, v1;
        #pragma unroll
        for (int j = 0; j < 8; ++j) { v0[j] = f2bf(vpre[j]); v1[j] = f2bf(vpre[j + 8]); }
        *reinterpret_cast<u16x8*>(vd_ + ((vb)      ^ vsw)) = v0;
        *reinterpret_cast<u16x8*>(vd_ + ((vb + 16) ^ vsw)) = v1;
    };

    // ---- prologue: tile 0 -> buf 0 ----
    {
        const f32x4* kp = reinterpret_cast<const f32x4*>(Kbase + (size_t)kr * Dn + kc);
        #pragma unroll
        for (int i = 0; i < 4; ++i) kpre[i] = kp[i];
        const float* vp = Vbase + (size_t)vk0 * Dn + vd;
        #pragma unroll
        for (int i = 0; i < 16; ++i) vpre[i] = vp[(size_t)i * Dn];
    }
    stage_write(0);
    __syncthreads();

    f32x4 acc[4] = {{0.f,0.f,0.f,0.f},{0.f,0.f,0.f,0.f},{0.f,0.f,0.f,0.f},{0.f,0.f,0.f,0.f}};
    float mrow = -1e30f;   // running max for q = ln (replicated over the 4 lane-groups)
    float lrow = 0.f;

    int p = 0;
    for (int kt = 0; kt < nkt; ++kt, p ^= 1) {
        const bool has_next = (kt + 1 < nkt);
        char* kcur = p ? kls1 : kls0;
        char* vcur = p ? vls1 : vls0;

        // ---- issue next tile's global loads (consumed by stage_write below) ----
        if (has_next) {
            const f32x4* kp = reinterpret_cast<const f32x4*>(Kbase + (size_t)((kt + 1) * 64 + kr) * Dn + kc);
            #pragma unroll
            for (int i = 0; i < 4; ++i) kpre[i] = kp[i];
            const float* vp = Vbase + (size_t)((kt + 1) * 64 + vk0) * Dn + vd;
            #pragma unroll
            for (int i = 0; i < 16; ++i) vpre[i] = vp[(size_t)i * Dn];
        }

        // ---- QK^T (swapped): st[t][j] = S[q=ln][k = kt*64 + 16t + lg*4 + j] ----
        f32x4 st[4] = {{0.f,0.f,0.f,0.f},{0.f,0.f,0.f,0.f},{0.f,0.f,0.f,0.f},{0.f,0.f,0.f,0.f}};
        #pragma unroll
        for (int t = 0; t < 4; ++t) {
            const int r = 16 * t + ln, rsw = (r & 7) << 4;
            bf16x8 ak0 = *reinterpret_cast<const bf16x8*>(kcur + ((r * 128 + lg * 16)      ^ rsw));
            st[t] = __builtin_amdgcn_mfma_f32_16x16x32_bf16(ak0, bq0, st[t], 0, 0, 0);
            bf16x8 ak1 = *reinterpret_cast<const bf16x8*>(kcur + ((r * 128 + lg * 16 + 64) ^ rsw));
            st[t] = __builtin_amdgcn_mfma_f32_16x16x32_bf16(ak1, bq1, st[t], 0, 0, 0);
        }

        // ---- mask (partial last tile only; block-uniform branch) ----
        const int kb0 = kt * 64 + lg * 4;
        if (kt * 64 + 64 > valid) {
            #pragma unroll
            for (int t = 0; t < 4; ++t)
                #pragma unroll
                for (int j = 0; j < 4; ++j)
                    if (kb0 + 16 * t + j >= valid) st[t][j] = -1e30f;
        }

        // ---- row max (q=ln): in-register tree + 2 shuffles ----
        float mx;
        {
            float a0 = fmaxf(fmaxf(st[0][0], st[0][1]), fmaxf(st[0][2], st[0][3]));
            float a1 = fmaxf(fmaxf(st[1][0], st[1][1]), fmaxf(st[1][2], st[1][3]));
            float a2 = fmaxf(fmaxf(st[2][0], st[2][1]), fmaxf(st[2][2], st[2][3]));
            float a3 = fmaxf(fmaxf(st[3][0], st[3][1]), fmaxf(st[3][2], st[3][3]));
            mx = fmaxf(fmaxf(a0, a1), fmaxf(a2, a3));
            mx = fmaxf(mx, __shfl_xor(mx, 16, 64));
            mx = fmaxf(mx, __shfl_xor(mx, 32, 64));
        }

        // ---- deferred rescale (T13) ----
        if (__any(mx - mrow > DEFER_THR)) {
            const float mn = fmaxf(mrow, mx);
            const float rs = exp2f(mrow - mn);
            mrow = mn;
            lrow *= rs;
            #pragma unroll
            for (int j = 0; j < 4; ++j) {
                const float rsj = __shfl(rs, lg * 4 + j, 64);  // rescale for q = lg*4+j
                #pragma unroll
                for (int t = 0; t < 4; ++t) acc[t][j] *= rsj;
            }
        }

        // ---- P = exp2(st - mrow): 4 x ds_write_b64, running sum ----
        float rsum = 0.f;
        const int psw = (ln & 7) << 4;
        #pragma unroll
        for (int t = 0; t < 4; ++t) {
            u16x4 pk;
            #pragma unroll
            for (int j = 0; j < 4; ++j) {
                const float pv = exp2f(st[t][j] - mrow);   // masked -> 0 exactly
                rsum += pv;
                pk[j] = f2bf(pv);
            }
            *reinterpret_cast<u16x4*>(pwb + ((ln * 128 + 32 * t + 8 * lg) ^ psw)) = pk;
        }
        rsum += __shfl_xor(rsum, 16, 64);
        rsum += __shfl_xor(rsum, 32, 64);
        lrow += rsum;
        // plds is per-wave; intra-wave DS order + compiler lgkmcnt protect the reads below.

        // ---- PV: acc[q=lg*4+j][d=16t+ln] += P[16q x 64k] * V[64k x 64d] ----
        #pragma unroll
        for (int s = 0; s < 2; ++s) {
            bf16x8 pa = *reinterpret_cast<const bf16x8*>(pwb + ((ln * 128 + lg * 16 + 64 * s) ^ psw));
            #pragma unroll
            for (int t = 0; t < 4; ++t) {
                const int r = 16 * t + ln, rsw = (r & 7) << 4;
                bf16x8 bv = *reinterpret_cast<const bf16x8*>(vcur + ((r * 128 + lg * 16 + 64 * s) ^ rsw));
                acc[t] = __builtin_amdgcn_mfma_f32_16x16x32_bf16(pa, bv, acc[t], 0, 0, 0);
            }
        }

        // ---- write next tile into the other buffer; single barrier per tile ----
        if (has_next) stage_write(p ^ 1);
        __syncthreads();
    }

    // ---- epilogue: O[q][d] = acc / l ----
    const float invl = 1.0f / lrow;   // for q = ln
    float inv[4];
    #pragma unroll
    for (int j = 0; j < 4; ++j) inv[j] = __shfl(invl, lg * 4 + j, 64);
    float* Orow = O + ((size_t)b * Ln + qbase) * Dn;
    #pragma unroll
    for (int t = 0; t < 4; ++t) {
        #pragma unroll
        for (int j = 0; j < 4; ++j) {
            const int q = lg * 4 + j;
            const int d = 16 * t + ln;
            Orow[(size_t)q * Dn + d] = acc[t][j] * inv[j];
        }
    }
}

extern "C" void kernel_launch(void* const* d_in, const int* in_sizes, int n_in,
                              void* d_out, int out_size, void* d_ws, size_t ws_size,
                              hipStream_t stream) {
    const float* Q = (const float*)d_in[0];
    const float* K = (const float*)d_in[1];
    const float* V = (const float*)d_in[2];
    const int* VL = (const int*)d_in[3];
    float* O = (float*)d_out;
    flash_attn<<<Bn * 16, 256, 0, stream>>>(Q, K, V, VL, O);
}